// Round 6
// baseline (141.670 us; speedup 1.0000x reference)
//
#include <hip/hip_runtime.h>

// HardPartPyramidPooling: x(16,256,32,16,11) fp32, labels(16,32,176) int,
// out(16,256,32,16) fp32.  out[n][c][s][p] = sum/cnt + max (0 if cnt==0),
// max floored at NEG_FILL=-100 (reference init).
//
// R6 (kernel-side ~33us -> target ~20): persistent block over 8 channel-group
// tiles of one (n,s):
//  - bucket labels ONCE per block (was 16x per ns: ~350cyc of serialized
//    same-address LDS atomics each).
//  - double-buffered tile, ONE barrier per tile: loads(t+1) -> gather(t,bufA)
//    -> store(t+1,bufB) -> sync.  Write-to-B vs read-from-A is race-free;
//    B's old tile was last read before the previous barrier.
//  - amortizes prologue (div-by-44 addr setup, label vmcnt, perm zero) 8x.

constexpr int C   = 256;
constexpr int S   = 32;
constexpr int HW  = 176;        // 16*11
constexpr int P   = 16;
constexpr int ROW = S * HW;     // 5632 floats per (n,c)
constexpr int GC  = 16;         // channels per tile
constexpr int NT  = 8;          // tiles per block
constexpr int PITCH = 178;      // tile row pitch (even: float2 align, 16 banks)
constexpr int BCAP  = 64;       // bucket capacity (max count ~25 for this data)
constexpr float NEG_FILL = -100.0f;

__global__ __launch_bounds__(256) void hpp_kernel(
    const float* __restrict__ x,
    const int*   __restrict__ labels,
    float*       __restrict__ out)
{
    __shared__ float         tile[2][GC * PITCH];  // 22.25 KB
    __shared__ unsigned char perm[P * BCAP];       // 1 KB  [p][slot] = pos
    __shared__ int           cnt[P];

    const int tid  = threadIdx.x;
    const int blk  = blockIdx.x;       // ns*2 + half
    const int ns   = blk >> 1, half = blk & 1;
    const int n    = ns >> 5,  s    = ns & 31;
    const int cg0  = half * NT;        // first channel-group (0 or 8)

    // ---- label load first (its wait leaves tile-0 loads in flight) ----
    const int* ln = labels + (size_t)ns * HW;
    int lab = 0;
    if (tid < HW) lab = ln[tid];

    // ---- per-thread slot decomposition: 704 float4 / tile, 44 per row ----
    const int f0 = tid, f1 = tid + 256, f2 = tid + 512;
    const int r0 = f0 / 44, j0 = f0 - r0 * 44;
    const int r1 = f1 / 44, j1 = f1 - r1 * 44;
    const int r2 = f2 / 44, j2 = f2 - r2 * 44;
    const bool has2 = (f2 < GC * 44);

    const float* xb0 = x + (size_t)(n * C + cg0 * GC) * ROW + s * HW;
    const float* a0 = xb0 + (size_t)r0 * ROW + j0 * 4;
    const float* a1 = xb0 + (size_t)r1 * ROW + j1 * 4;
    const float* a2 = xb0 + (size_t)r2 * ROW + j2 * 4;
    constexpr size_t STEP = (size_t)GC * ROW;      // floats between tiles

    // ---- issue tile-0 loads ----
    float4 v0 = *(const float4*)a0;
    float4 v1 = *(const float4*)a1;
    float4 v2 = make_float4(0.f, 0.f, 0.f, 0.f);
    if (has2) v2 = *(const float4*)a2;

    // ---- zero perm + counters, bucket once (overlaps tile-0 vmcnt) ----
    ((unsigned*)perm)[tid] = 0u;
    if (tid < P) cnt[tid] = 0;
    __syncthreads();
    if (tid < HW) {
        int r = atomicAdd(&cnt[lab], 1);
        if (r < BCAP) perm[(lab << 6) + r] = (unsigned char)tid;
    }
    __syncthreads();

    // ---- store tile 0 into buf 0 ----
    {
        float2* t0 = (float2*)&tile[0][r0 * PITCH + j0 * 4];
        t0[0] = make_float2(v0.x, v0.y); t0[1] = make_float2(v0.z, v0.w);
        float2* t1 = (float2*)&tile[0][r1 * PITCH + j1 * 4];
        t1[0] = make_float2(v1.x, v1.y); t1[1] = make_float2(v1.z, v1.w);
        if (has2) {
            float2* t2 = (float2*)&tile[0][r2 * PITCH + j2 * 4];
            t2[0] = make_float2(v2.x, v2.y); t2[1] = make_float2(v2.z, v2.w);
        }
    }
    __syncthreads();

    // ---- gather setup (stable after barriers above) ----
    const int p = tid >> 4, c = tid & 15;
    const int k  = min(cnt[p], BCAP);
    const int kf = k & ~3;
    const unsigned char* pp = &perm[p << 6];
    float* op = out + ((size_t)(n * C + cg0 * GC + c) * S + s) * P + p;

    int cur = 0;
    #pragma unroll
    for (int t = 0; t < NT; ++t) {
        // -- prefetch tile t+1 --
        const bool more = (t < NT - 1);
        if (more) {
            const size_t off = (size_t)(t + 1) * STEP;
            v0 = *(const float4*)(a0 + off);
            v1 = *(const float4*)(a1 + off);
            if (has2) v2 = *(const float4*)(a2 + off);
        }

        // -- gather-reduce from tile[cur] --
        const float* tc = &tile[cur][c * PITCH];
        float s0 = 0.f, s1 = 0.f, m0 = NEG_FILL, m1 = NEG_FILL;
        for (int j = 0; j < kf; j += 4) {
            unsigned u = *(const unsigned*)&pp[j];   // broadcast in p-group
            float b0 = tc[u & 0xFF];
            float b1 = tc[(u >> 8) & 0xFF];
            float b2 = tc[(u >> 16) & 0xFF];
            float b3 = tc[u >> 24];
            s0 += b0; m0 = fmaxf(m0, b0);
            s1 += b1; m1 = fmaxf(m1, b1);
            s0 += b2; m0 = fmaxf(m0, b2);
            s1 += b3; m1 = fmaxf(m1, b3);
        }
        if (kf < k) {                                // 1..3 tail
            unsigned u = *(const unsigned*)&pp[kf];
            float b0 = tc[u & 0xFF];
            float b1 = tc[(u >> 8) & 0xFF];
            float b2 = tc[(u >> 16) & 0xFF];
            s0 += b0; m0 = fmaxf(m0, b0);
            if (kf + 1 < k) { s1 += b1; m1 = fmaxf(m1, b1); }
            if (kf + 2 < k) { s0 += b2; m0 = fmaxf(m0, b2); }
        }
        op[(size_t)t * (GC * S * P)] =
            (k > 0) ? (s0 + s1) / (float)k + fmaxf(m0, m1) : 0.f;

        // -- store prefetch into the other buffer; ONE barrier per tile --
        if (more) {
            const int nxt = cur ^ 1;
            float2* t0 = (float2*)&tile[nxt][r0 * PITCH + j0 * 4];
            t0[0] = make_float2(v0.x, v0.y); t0[1] = make_float2(v0.z, v0.w);
            float2* t1 = (float2*)&tile[nxt][r1 * PITCH + j1 * 4];
            t1[0] = make_float2(v1.x, v1.y); t1[1] = make_float2(v1.z, v1.w);
            if (has2) {
                float2* t2 = (float2*)&tile[nxt][r2 * PITCH + j2 * 4];
                t2[0] = make_float2(v2.x, v2.y); t2[1] = make_float2(v2.z, v2.w);
            }
            __syncthreads();
            cur = nxt;
        }
    }
}

extern "C" void kernel_launch(void* const* d_in, const int* in_sizes, int n_in,
                              void* d_out, int out_size, void* d_ws, size_t ws_size,
                              hipStream_t stream) {
    const float* x      = (const float*)d_in[0];
    const int*   labels = (const int*)d_in[1];
    float*       out    = (float*)d_out;

    const int ns_total = in_sizes[1] / HW;          // 512
    const int nblk     = ns_total * 2;              // 1024
    hpp_kernel<<<nblk, 256, 0, stream>>>(x, labels, out);
}

// Round 9
// 138.946 us; speedup vs baseline: 1.0196x; 1.0196x over previous
//
#include <hip/hip_runtime.h>

// HardPartPyramidPooling: x(16,256,32,16,11) fp32, labels(16,32,176) int,
// out(16,256,32,16) fp32.  out[n][c][s][p] = sum/cnt + max (0 if cnt==0),
// max floored at NEG_FILL=-100 (reference init).
//
// R7c: compile fix — global_load_lds size must be a LITERAL at the call site
// (clang validates pre-instantiation), so the wrapper hardcodes 16.
// Block = (n,c): the 5632-float slab is FULLY CONTIGUOUS (22.5 KB) ->
// perfect HBM stream, staged via global_load_lds width=16 (lane-linear dest,
// no VGPR roundtrip, no ds_writes, ONE barrier).  Per-(n,s) label CSR built
// once by a prep kernel (512 blocks -> 256 B records, L3-hot: each n's 8 KB
// meta shared by 256 main blocks).  Gather: thread (s,p) walks bucket p of
// slice s from the LDS tile; first 16 indices preloaded as u32 words.

constexpr int C   = 256;
constexpr int S   = 32;
constexpr int HW  = 176;        // 16*11
constexpr int P   = 16;
constexpr int ROW = S * HW;     // 5632 floats per (n,c), contiguous
constexpr int REC = 256;        // meta record bytes per (n,s):
                                // [0..223] perm u8 (buckets 4B-padded)
                                // [224..239] cnt u8, [240..255] off u8
constexpr float NEG_FILL = -100.0f;

// ---------------- prep: build CSR perm per (n,s) ----------------
__global__ __launch_bounds__(256) void prep_kernel(const int* __restrict__ labels,
                                                   unsigned char* __restrict__ ws)
{
    __shared__ int cnt[P], off[P];
    __shared__ unsigned char rec[REC];
    const int tid = threadIdx.x, ns = blockIdx.x;

    int lab = 0, r = 0;
    if (tid < HW) lab = labels[(size_t)ns * HW + tid];
    if (tid < P) cnt[tid] = 0;
    __syncthreads();
    if (tid < HW) r = atomicAdd(&cnt[lab], 1);
    __syncthreads();
    if (tid == 0) {
        int run = 0;
        #pragma unroll
        for (int p = 0; p < P; ++p) { off[p] = run; run += (cnt[p] + 3) & ~3; }
    }
    __syncthreads();
    if (tid < HW) rec[off[lab] + r] = (unsigned char)tid;
    if (tid < P) {
        rec[224 + tid] = (unsigned char)cnt[tid];
        rec[240 + tid] = (unsigned char)off[tid];
    }
    __syncthreads();
    if (tid < REC / 4)   // coalesced record write (pad bytes arbitrary, never used)
        ((unsigned*)(ws + (size_t)ns * REC))[tid] = ((const unsigned*)rec)[tid];
}

// ---------------- main ----------------
__device__ __forceinline__ void gload_lds16(const void* g, void* l) {
    __builtin_amdgcn_global_load_lds(
        (const __attribute__((address_space(1))) void*)g,
        (__attribute__((address_space(3))) void*)l, 16, 0, 0);
}

__global__ __launch_bounds__(256) void hpp_main(const float* __restrict__ x,
                                                const unsigned char* __restrict__ ws,
                                                float* __restrict__ out)
{
    __shared__ float         tile[ROW];       // 22528 B
    __shared__ unsigned char meta[S * REC];   // 8192 B

    const int tid = threadIdx.x;
    const int blk = blockIdx.x;               // n*C + c
    const int n   = blk >> 8;

    const float*         xb = x  + (size_t)blk * ROW;
    const unsigned char* mb = ws + (size_t)n * (S * REC);

    // -- DMA meta: 8192 B = 512 uint4, lane-linear, 2 slots --
    #pragma unroll
    for (int i = 0; i < 2; ++i)
        gload_lds16((const uint4*)mb + i * 256 + tid,
                    (uint4*)meta + i * 256 + tid);
    // -- DMA tile: 1408 float4, lane-linear, 5 full slots + half slot --
    #pragma unroll
    for (int i = 0; i < 5; ++i)
        gload_lds16((const float4*)xb + i * 256 + tid,
                    (float4*)tile + i * 256 + tid);
    if (tid < 128)
        gload_lds16((const float4*)xb + 5 * 256 + tid,
                    (float4*)tile + 5 * 256 + tid);

    __syncthreads();   // drains vmcnt (compiler emits the waitcnt)

    // -- gather: thread (s,p); two s per thread (s and s+16) --
    const int p   = tid & 15;
    const int sh  = tid >> 4;                 // 0..15

    #pragma unroll
    for (int q = 0; q < 2; ++q) {
        const int s = sh + 16 * q;
        const unsigned char* rec = &meta[s * REC];
        const int k    = rec[224 + p];
        const int base = rec[240 + p];        // 4-aligned
        const float*    tc = &tile[s * HW];
        const unsigned* pw = (const unsigned*)(rec + base);

        // preload first 16 indices (4 independent ds_reads, chain-free)
        unsigned w0 = pw[0], w1 = pw[1], w2 = pw[2], w3 = pw[3];

        float a0 = 0.f, a1 = 0.f, m0 = NEG_FILL, m1 = NEG_FILL;
        // reads unconditional (pad indices stay in-LDS); accumulate predicated
        #define CH(w, jb)                                                  \
            do { if (k > (jb)) {                                           \
                float b0 = tc[(w) & 0xFF];                                 \
                float b1 = tc[((w) >> 8) & 0xFF];                          \
                float b2 = tc[((w) >> 16) & 0xFF];                         \
                float b3 = tc[(w) >> 24];                                  \
                a0 += b0; m0 = fmaxf(m0, b0);                              \
                if (k > (jb) + 1) { a1 += b1; m1 = fmaxf(m1, b1); }        \
                if (k > (jb) + 2) { a0 += b2; m0 = fmaxf(m0, b2); }        \
                if (k > (jb) + 3) { a1 += b3; m1 = fmaxf(m1, b3); }        \
            } } while (0)
        CH(w0, 0); CH(w1, 4); CH(w2, 8); CH(w3, 12);
        for (int j = 16; j < k; j += 4) {     // rare: buckets with k>16
            unsigned w = pw[j >> 2];
            CH(w, j);
        }
        #undef CH

        float res = (k > 0) ? (a0 + a1) / (float)k + fmaxf(m0, m1) : 0.f;
        out[((size_t)blk * S + s) * P + p] = res;   // 64B-contiguous per s-row
    }
}

// ---------------- naive fallback (only if ws too small) ----------------
__global__ void hpp_naive(const float* __restrict__ x,
                          const int* __restrict__ labels,
                          float* __restrict__ out)
{
    int t = blockIdx.x * 256 + threadIdx.x;   // (ns, c, p)
    int p = t & 15, c = (t >> 4) & 255, ns = t >> 12;
    int n = ns >> 5, s = ns & 31;
    const int*   ln  = labels + (size_t)ns * HW;
    const float* row = x + ((size_t)(n * C + c) * S + s) * HW;
    float sum = 0.f, mx = NEG_FILL; int k = 0;
    for (int i = 0; i < HW; ++i)
        if (ln[i] == p) { float v = row[i]; sum += v; mx = fmaxf(mx, v); k++; }
    out[((size_t)(n * C + c) * S + s) * P + p] = k ? sum / (float)k + mx : 0.f;
}

extern "C" void kernel_launch(void* const* d_in, const int* in_sizes, int n_in,
                              void* d_out, int out_size, void* d_ws, size_t ws_size,
                              hipStream_t stream) {
    const float* x      = (const float*)d_in[0];
    const int*   labels = (const int*)d_in[1];
    float*       out    = (float*)d_out;

    const int ns_total = in_sizes[1] / HW;              // 512
    const size_t need  = (size_t)ns_total * REC;        // 128 KB

    if (ws_size >= need) {
        prep_kernel<<<ns_total, 256, 0, stream>>>(labels, (unsigned char*)d_ws);
        hpp_main<<<ns_total / S * C, 256, 0, stream>>>(x, (const unsigned char*)d_ws, out);
    } else {
        hpp_naive<<<(out_size + 255) / 256, 256, 0, stream>>>(x, labels, out);
    }
}